// Round 4
// baseline (16.223 us; speedup 1.0000x reference)
//
#include <hip/hip_runtime.h>
#include <hip/hip_bf16.h>

// Fully-fused analytic collapse of the 4-qubit circuit:
//   out = psi(theta)^T A psi(theta),  A = Re(U^dag Z0 U)  (U fixed by weights)
// expanded into an 81-coefficient multilinear polynomial in {1,cos,sin} per angle.
// ONE kernel: each block redundantly computes the 81 coefficients (cheap,
// overlapped across blocks), then evaluates the polynomial for its tile.
// Thread tile: 4 cols x 2 output rows (3 input rows).
// NOTE: use __sinf/__cosf (native v_sin_f32/v_cos_f32 path) — NOT __sincosf,
// which can lower to the accurate ocml sincos (~60+ VALU ops per call).

__device__ __forceinline__ void compute_W_block(const float* __restrict__ wts,
                                                float* __restrict__ Wsh) {
    __shared__ float2 U[16][16];   // U[col][i]
    __shared__ float  A[16][16];
    const int tid = threadIdx.x;

    if (tid < 16) {
        float2 v[16];
        #pragma unroll
        for (int i = 0; i < 16; ++i) v[i] = make_float2(i == tid ? 1.f : 0.f, 0.f);

        #pragma unroll
        for (int layer = 0; layer < 2; ++layer) {
            #pragma unroll
            for (int q = 0; q < 4; ++q) {
                const int p = 3 - q;                 // wire q -> bit (3-q)
                const float thx = wts[(layer * 4 + q) * 3 + 0];
                const float thy = wts[(layer * 4 + q) * 3 + 1];
                const float thz = wts[(layer * 4 + q) * 3 + 2];
                // RX: [[c, -i s], [-i s, c]]
                {
                    float c = __cosf(0.5f * thx), s = __sinf(0.5f * thx);
                    #pragma unroll
                    for (int i = 0; i < 16; ++i) if (!((i >> p) & 1)) {
                        const int j = i | (1 << p);
                        float2 a = v[i], b = v[j];
                        v[i] = make_float2(c * a.x + s * b.y, c * a.y - s * b.x);
                        v[j] = make_float2(c * b.x + s * a.y, c * b.y - s * a.x);
                    }
                }
                // RY: [[c, -s], [s, c]]
                {
                    float c = __cosf(0.5f * thy), s = __sinf(0.5f * thy);
                    #pragma unroll
                    for (int i = 0; i < 16; ++i) if (!((i >> p) & 1)) {
                        const int j = i | (1 << p);
                        float2 a = v[i], b = v[j];
                        v[i] = make_float2(c * a.x - s * b.x, c * a.y - s * b.y);
                        v[j] = make_float2(s * a.x + c * b.x, s * a.y + c * b.y);
                    }
                }
                // RZ: diag(e^{-i t/2}, e^{+i t/2})
                {
                    float c = __cosf(0.5f * thz), s = __sinf(0.5f * thz);
                    #pragma unroll
                    for (int i = 0; i < 16; ++i) {
                        float2 a = v[i];
                        if (!((i >> p) & 1)) v[i] = make_float2(c * a.x + s * a.y, c * a.y - s * a.x);
                        else                 v[i] = make_float2(c * a.x - s * a.y, c * a.y + s * a.x);
                    }
                }
            }
            // CNOT(0,1), CNOT(2,3), CNOT(0,2), CNOT(1,3)
            #pragma unroll
            for (int ee = 0; ee < 4; ++ee) {
                const int cc[4] = {0, 2, 0, 1}, tt[4] = {1, 3, 2, 3};
                const int pc = 3 - cc[ee], pt = 3 - tt[ee];
                #pragma unroll
                for (int i = 0; i < 16; ++i) if (((i >> pc) & 1) && !((i >> pt) & 1)) {
                    const int j = i | (1 << pt);
                    float2 t = v[i]; v[i] = v[j]; v[j] = t;
                }
            }
        }
        #pragma unroll
        for (int i = 0; i < 16; ++i) U[tid][i] = v[i];
    }
    __syncthreads();

    // A[j][k] = Re( sum_i conj(U[i][j]) z_i U[i][k] ),  z_i = (i&8) ? -1 : +1
    {
        const int j = tid >> 4, k = tid & 15;
        float re = 0.f;
        #pragma unroll
        for (int i = 0; i < 16; ++i) {
            const float z = (i & 8) ? -1.f : 1.f;
            float2 a = U[j][i], b = U[k][i];
            re += z * (a.x * b.x + a.y * b.y);
        }
        A[j][k] = re;
    }
    __syncthreads();

    // Project onto {1,cos,sin}^4 using exact projector sparsity:
    //   W[e] = (1/16) * sum_b parity(b&mask1) * A[b][b^mask2]
    if (tid < 84) {
        float r = 0.f;
        if (tid < 81) {
            const int e = tid;
            const int d0 = e / 27, d1 = (e / 9) % 3, d2 = (e / 3) % 3, d3 = e % 3;
            int mask1 = 0, mask2 = 0;
            if (d0 == 1) mask1 |= 8; else if (d0 == 2) mask2 |= 8;
            if (d1 == 1) mask1 |= 4; else if (d1 == 2) mask2 |= 4;
            if (d2 == 1) mask1 |= 2; else if (d2 == 2) mask2 |= 2;
            if (d3 == 1) mask1 |= 1; else if (d3 == 2) mask2 |= 1;
            float sum = 0.f;
            #pragma unroll
            for (int b = 0; b < 16; ++b) {
                const float sgn = (__popc(b & mask1) & 1) ? -1.f : 1.f;
                sum += sgn * A[b][b ^ mask2];
            }
            r = sum * 0.0625f;
        }
        Wsh[tid] = r;
    }
    __syncthreads();
}

__global__ __launch_bounds__(256) void qconv_fused(
        const float* __restrict__ x, const float* __restrict__ wts,
        float* __restrict__ out) {
    __shared__ __align__(16) float Wsh[84];
    compute_W_block(wts, Wsh);

    // Hoist coefficients LDS -> registers (ds_read_b128), amortized over 8 outputs.
    float w[81];
    {
        const float4* W4 = (const float4*)Wsh;
        #pragma unroll
        for (int i = 0; i < 20; ++i) {
            float4 v4 = W4[i];
            w[4*i+0] = v4.x; w[4*i+1] = v4.y; w[4*i+2] = v4.z; w[4*i+3] = v4.w;
        }
        w[80] = Wsh[80];
    }

    // group = (img, row-pair); 32 lanes x 4 cols cover one 127-wide row pair
    const int g    = blockIdx.x * 8 + (threadIdx.x >> 5);   // 0..6143
    const int l    = threadIdx.x & 31;
    const int img  = g >> 6;                                // /64
    const int pair = g & 63;
    const int h    = pair * 2;
    const int nr   = (pair == 63) ? 1 : 2;                  // output rows in this group
    const int col0 = l * 4;
    const int ncols = (l == 31) ? 3 : 4;
    const int base = img * 16384 + h * 128 + col0;          // 16B-aligned

    float r0[5], r1[5], r2[5];
    {
        float4 a4 = *(const float4*)(x + base);
        float4 b4 = *(const float4*)(x + base + 128);
        r0[0]=a4.x; r0[1]=a4.y; r0[2]=a4.z; r0[3]=a4.w;
        r1[0]=b4.x; r1[1]=b4.y; r1[2]=b4.z; r1[3]=b4.w;
        r0[4]=0.f; r1[4]=0.f; r2[0]=0.f; r2[1]=0.f; r2[2]=0.f; r2[3]=0.f; r2[4]=0.f;
        if (ncols == 4) { r0[4] = x[base + 4]; r1[4] = x[base + 132]; }
        if (nr == 2) {
            float4 c4 = *(const float4*)(x + base + 256);
            r2[0]=c4.x; r2[1]=c4.y; r2[2]=c4.z; r2[3]=c4.w;
            if (ncols == 4) r2[4] = x[base + 260];
        }
    }

    float c0a[5], s0a[5], c1a[5], s1a[5], c2a[5], s2a[5];
    #pragma unroll
    for (int j = 0; j < 5; ++j) {
        s0a[j] = __sinf(r0[j]); c0a[j] = __cosf(r0[j]);
        s1a[j] = __sinf(r1[j]); c1a[j] = __cosf(r1[j]);
        s2a[j] = __sinf(r2[j]); c2a[j] = __cosf(r2[j]);
    }

    // eval(top-left, top-right, bottom-left, bottom-right)
    auto eval = [&](float c0, float s0, float c1, float s1,
                    float c2, float s2, float c3, float s3) -> float {
        float acc = 0.f;
        #pragma unroll
        for (int e0 = 0; e0 < 3; ++e0) {
            const float u0 = (e0 == 0) ? 1.f : ((e0 == 1) ? c0 : s0);
            float a0 = 0.f;
            #pragma unroll
            for (int e1 = 0; e1 < 3; ++e1) {
                const float u1 = (e1 == 0) ? 1.f : ((e1 == 1) ? c1 : s1);
                float a1 = 0.f;
                #pragma unroll
                for (int e2 = 0; e2 < 3; ++e2) {
                    const float u2 = (e2 == 0) ? 1.f : ((e2 == 1) ? c2 : s2);
                    const int idx = ((e0 * 3 + e1) * 3 + e2) * 3;
                    const float a2 = w[idx] + w[idx + 1] * c3 + w[idx + 2] * s3;
                    a1 += a2 * u2;
                }
                a0 += a1 * u1;
            }
            acc += a0 * u0;
        }
        return acc;
    };

    float ev0[4], ev1[4];
    #pragma unroll
    for (int k = 0; k < 4; ++k) {
        ev0[k] = eval(c0a[k], s0a[k], c0a[k+1], s0a[k+1],
                      c1a[k], s1a[k], c1a[k+1], s1a[k+1]);
        ev1[k] = eval(c1a[k], s1a[k], c1a[k+1], s1a[k+1],
                      c2a[k], s2a[k], c2a[k+1], s2a[k+1]);
    }

    const int ob0 = (img * 127 + h) * 127 + col0;
    #pragma unroll
    for (int k = 0; k < 4; ++k) if (k < ncols) out[ob0 + k] = ev0[k];
    if (nr == 2) {
        const int ob1 = ob0 + 127;
        #pragma unroll
        for (int k = 0; k < 4; ++k) if (k < ncols) out[ob1 + k] = ev1[k];
    }
}

extern "C" void kernel_launch(void* const* d_in, const int* in_sizes, int n_in,
                              void* d_out, int out_size, void* d_ws, size_t ws_size,
                              hipStream_t stream) {
    const float* x   = (const float*)d_in[0];
    const float* wts = (const float*)d_in[1];
    float* out = (float*)d_out;

    // 96 images x 64 row-pair groups, 8 groups per 256-thread block
    const int blocks = (96 * 64) / 8;   // 768
    qconv_fused<<<blocks, 256, 0, stream>>>(x, wts, out);
}

// Round 5
// 14.520 us; speedup vs baseline: 1.1173x; 1.1173x over previous
//
#include <hip/hip_runtime.h>
#include <hip/hip_bf16.h>

// Fully-fused analytic collapse of the 4-qubit circuit:
//   out = psi(theta)^T A psi(theta),  A = Re(U^dag Z0 U)  (U fixed by weights)
// expanded into an 81-coefficient multilinear polynomial in {1,cos,sin} per angle.
// R5: (1) hoist per-thread loads + sincos ABOVE the per-block W computation so
// waves 1-3 do memory+trig while wave 0 runs the serial U-simulation;
// (2) pack the two row evals (ev0/ev1) into ext_vector float2 -> v_pk_fma_f32.

using f32x2 = __attribute__((ext_vector_type(2))) float;

__device__ __forceinline__ void compute_W_block(const float* __restrict__ wts,
                                                float* __restrict__ Wsh) {
    __shared__ float2 U[16][16];   // U[col][i]
    __shared__ float  A[16][16];
    const int tid = threadIdx.x;

    if (tid < 16) {
        float2 v[16];
        #pragma unroll
        for (int i = 0; i < 16; ++i) v[i] = make_float2(i == tid ? 1.f : 0.f, 0.f);

        #pragma unroll
        for (int layer = 0; layer < 2; ++layer) {
            #pragma unroll
            for (int q = 0; q < 4; ++q) {
                const int p = 3 - q;                 // wire q -> bit (3-q)
                const float thx = wts[(layer * 4 + q) * 3 + 0];
                const float thy = wts[(layer * 4 + q) * 3 + 1];
                const float thz = wts[(layer * 4 + q) * 3 + 2];
                // RX: [[c, -i s], [-i s, c]]
                {
                    float c = __cosf(0.5f * thx), s = __sinf(0.5f * thx);
                    #pragma unroll
                    for (int i = 0; i < 16; ++i) if (!((i >> p) & 1)) {
                        const int j = i | (1 << p);
                        float2 a = v[i], b = v[j];
                        v[i] = make_float2(c * a.x + s * b.y, c * a.y - s * b.x);
                        v[j] = make_float2(c * b.x + s * a.y, c * b.y - s * a.x);
                    }
                }
                // RY: [[c, -s], [s, c]]
                {
                    float c = __cosf(0.5f * thy), s = __sinf(0.5f * thy);
                    #pragma unroll
                    for (int i = 0; i < 16; ++i) if (!((i >> p) & 1)) {
                        const int j = i | (1 << p);
                        float2 a = v[i], b = v[j];
                        v[i] = make_float2(c * a.x - s * b.x, c * a.y - s * b.y);
                        v[j] = make_float2(s * a.x + c * b.x, s * a.y + c * b.y);
                    }
                }
                // RZ: diag(e^{-i t/2}, e^{+i t/2})
                {
                    float c = __cosf(0.5f * thz), s = __sinf(0.5f * thz);
                    #pragma unroll
                    for (int i = 0; i < 16; ++i) {
                        float2 a = v[i];
                        if (!((i >> p) & 1)) v[i] = make_float2(c * a.x + s * a.y, c * a.y - s * a.x);
                        else                 v[i] = make_float2(c * a.x - s * a.y, c * a.y + s * a.x);
                    }
                }
            }
            // CNOT(0,1), CNOT(2,3), CNOT(0,2), CNOT(1,3)
            #pragma unroll
            for (int ee = 0; ee < 4; ++ee) {
                const int cc[4] = {0, 2, 0, 1}, tt[4] = {1, 3, 2, 3};
                const int pc = 3 - cc[ee], pt = 3 - tt[ee];
                #pragma unroll
                for (int i = 0; i < 16; ++i) if (((i >> pc) & 1) && !((i >> pt) & 1)) {
                    const int j = i | (1 << pt);
                    float2 t = v[i]; v[i] = v[j]; v[j] = t;
                }
            }
        }
        #pragma unroll
        for (int i = 0; i < 16; ++i) U[tid][i] = v[i];
    }
    __syncthreads();

    // A[j][k] = Re( sum_i conj(U[i][j]) z_i U[i][k] ),  z_i = (i&8) ? -1 : +1
    {
        const int j = tid >> 4, k = tid & 15;
        float re = 0.f;
        #pragma unroll
        for (int i = 0; i < 16; ++i) {
            const float z = (i & 8) ? -1.f : 1.f;
            float2 a = U[j][i], b = U[k][i];
            re += z * (a.x * b.x + a.y * b.y);
        }
        A[j][k] = re;
    }
    __syncthreads();

    // Project onto {1,cos,sin}^4 using exact projector sparsity:
    //   W[e] = (1/16) * sum_b parity(b&mask1) * A[b][b^mask2]
    if (tid < 84) {
        float r = 0.f;
        if (tid < 81) {
            const int e = tid;
            const int d0 = e / 27, d1 = (e / 9) % 3, d2 = (e / 3) % 3, d3 = e % 3;
            int mask1 = 0, mask2 = 0;
            if (d0 == 1) mask1 |= 8; else if (d0 == 2) mask2 |= 8;
            if (d1 == 1) mask1 |= 4; else if (d1 == 2) mask2 |= 4;
            if (d2 == 1) mask1 |= 2; else if (d2 == 2) mask2 |= 2;
            if (d3 == 1) mask1 |= 1; else if (d3 == 2) mask2 |= 1;
            float sum = 0.f;
            #pragma unroll
            for (int b = 0; b < 16; ++b) {
                const float sgn = (__popc(b & mask1) & 1) ? -1.f : 1.f;
                sum += sgn * A[b][b ^ mask2];
            }
            r = sum * 0.0625f;
        }
        Wsh[tid] = r;
    }
    __syncthreads();
}

__global__ __launch_bounds__(256) void qconv_fused(
        const float* __restrict__ x, const float* __restrict__ wts,
        float* __restrict__ out) {
    __shared__ __align__(16) float Wsh[84];

    // ---- Phase 0 (ALL waves): loads + trig, BEFORE the setup barrier ----
    const int g    = blockIdx.x * 8 + (threadIdx.x >> 5);   // 0..6143
    const int l    = threadIdx.x & 31;
    const int img  = g >> 6;                                // /64
    const int pair = g & 63;
    const int h    = pair * 2;
    const int nr   = (pair == 63) ? 1 : 2;                  // output rows in this group
    const int col0 = l * 4;
    const int ncols = (l == 31) ? 3 : 4;
    const int base = img * 16384 + h * 128 + col0;          // 16B-aligned

    float r0[5], r1[5], r2[5];
    {
        float4 a4 = *(const float4*)(x + base);
        float4 b4 = *(const float4*)(x + base + 128);
        r0[0]=a4.x; r0[1]=a4.y; r0[2]=a4.z; r0[3]=a4.w;
        r1[0]=b4.x; r1[1]=b4.y; r1[2]=b4.z; r1[3]=b4.w;
        r0[4]=0.f; r1[4]=0.f; r2[0]=0.f; r2[1]=0.f; r2[2]=0.f; r2[3]=0.f; r2[4]=0.f;
        if (ncols == 4) { r0[4] = x[base + 4]; r1[4] = x[base + 132]; }
        if (nr == 2) {
            float4 c4 = *(const float4*)(x + base + 256);
            r2[0]=c4.x; r2[1]=c4.y; r2[2]=c4.z; r2[3]=c4.w;
            if (ncols == 4) r2[4] = x[base + 260];
        }
    }

    // Packed trig: lane .x belongs to the row-h eval, .y to the row-(h+1) eval.
    // ctv[j] = (cos t-row, cos mid-row), cbv[j] = (cos mid-row, cos bot-row).
    f32x2 ctv[5], stv[5], cbv[5], sbv[5];
    #pragma unroll
    for (int j = 0; j < 5; ++j) {
        float s0 = __sinf(r0[j]), c0 = __cosf(r0[j]);
        float s1 = __sinf(r1[j]), c1 = __cosf(r1[j]);
        float s2 = __sinf(r2[j]), c2 = __cosf(r2[j]);
        ctv[j] = (f32x2){c0, c1};  stv[j] = (f32x2){s0, s1};
        cbv[j] = (f32x2){c1, c2};  sbv[j] = (f32x2){s1, s2};
    }

    // ---- Phase 1: per-block W (wave 0 works; waves 1-3 already did phase 0) ----
    compute_W_block(wts, Wsh);

    // Hoist coefficients LDS -> registers (ds_read_b128).
    float w[81];
    {
        const float4* W4 = (const float4*)Wsh;
        #pragma unroll
        for (int i = 0; i < 20; ++i) {
            float4 v4 = W4[i];
            w[4*i+0] = v4.x; w[4*i+1] = v4.y; w[4*i+2] = v4.z; w[4*i+3] = v4.w;
        }
        w[80] = Wsh[80];
    }

    // ---- Phase 2: packed polynomial eval (v_pk_fma_f32 path) ----
    f32x2 ev[4];
    #pragma unroll
    for (int k = 0; k < 4; ++k) {
        const f32x2 c0 = ctv[k],     s0 = stv[k];
        const f32x2 c1 = ctv[k + 1], s1 = stv[k + 1];
        const f32x2 c2 = cbv[k],     s2 = sbv[k];
        const f32x2 c3 = cbv[k + 1], s3 = sbv[k + 1];
        f32x2 acc = (f32x2){0.f, 0.f};
        #pragma unroll
        for (int e0 = 0; e0 < 3; ++e0) {
            f32x2 a0 = (f32x2){0.f, 0.f};
            #pragma unroll
            for (int e1 = 0; e1 < 3; ++e1) {
                f32x2 a1 = (f32x2){0.f, 0.f};
                #pragma unroll
                for (int e2 = 0; e2 < 3; ++e2) {
                    const int idx = ((e0 * 3 + e1) * 3 + e2) * 3;
                    f32x2 a2 = w[idx] + w[idx + 1] * c3 + w[idx + 2] * s3;
                    if (e2 == 0)      a1 += a2;
                    else if (e2 == 1) a1 += a2 * c2;
                    else              a1 += a2 * s2;
                }
                if (e1 == 0)      a0 += a1;
                else if (e1 == 1) a0 += a1 * c1;
                else              a0 += a1 * s1;
            }
            if (e0 == 0)      acc += a0;
            else if (e0 == 1) acc += a0 * c0;
            else              acc += a0 * s0;
        }
        ev[k] = acc;
    }

    const int ob0 = (img * 127 + h) * 127 + col0;
    #pragma unroll
    for (int k = 0; k < 4; ++k) if (k < ncols) out[ob0 + k] = ev[k].x;
    if (nr == 2) {
        const int ob1 = ob0 + 127;
        #pragma unroll
        for (int k = 0; k < 4; ++k) if (k < ncols) out[ob1 + k] = ev[k].y;
    }
}

extern "C" void kernel_launch(void* const* d_in, const int* in_sizes, int n_in,
                              void* d_out, int out_size, void* d_ws, size_t ws_size,
                              hipStream_t stream) {
    const float* x   = (const float*)d_in[0];
    const float* wts = (const float*)d_in[1];
    float* out = (float*)d_out;

    // 96 images x 64 row-pair groups, 8 groups per 256-thread block
    const int blocks = (96 * 64) / 8;   // 768
    qconv_fused<<<blocks, 256, 0, stream>>>(x, wts, out);
}